// Round 3
// baseline (445.393 us; speedup 1.0000x reference)
//
#include <hip/hip_runtime.h>
#include <hip/hip_bf16.h>
#include <math.h>

#define NN 50000
#define NE 800000
#define ET (NE + NN)

__device__ __forceinline__ float bf2f(unsigned short u) {
    return __uint_as_float(((unsigned)u) << 16);
}
__device__ __forceinline__ float lrelu(float e) {
    return e >= 0.f ? e : 0.2f * e;
}

// ---------- dtype detection ----------
__global__ void k_init(int* __restrict__ iflag, int* __restrict__ deg) {
    int i = blockIdx.x * 256 + threadIdx.x;
    if (i == 0) *iflag = 1;          // assume int64 until proven otherwise
    if (i < NN) deg[i] = 0;
}

// int width: read first NE u64 slots (in-bounds for both layouts). If data is
// int32, most slots combine two values -> >= 2^32 -> flag=0.
__global__ void k_detect(const unsigned long long* __restrict__ p, int* __restrict__ iflag) {
    int i = blockIdx.x * 256 + threadIdx.x;
    if (i < NE) {
        if (p[i] >= (unsigned long long)NN) *iflag = 0;
    }
}

// float dtype: for fp32 N(0,1) data, bits 14..7 of each u32 are uniform random
// mantissa bits; for bf16-pair data they are the exponent of a N(0,1) bf16
// value, concentrated in [96,140]. Count over 1024 words; threshold at 700.
__global__ __launch_bounds__(1024) void k_fdetect(const unsigned int* __restrict__ x,
                                                  int* __restrict__ fflag) {
    __shared__ int cnt[16];
    int t = threadIdx.x;
    unsigned w = x[t];
    unsigned e = (w >> 7) & 0xFFu;
    int c = (e >= 96 && e <= 140) ? 1 : 0;
    #pragma unroll
    for (int off = 32; off; off >>= 1) c += __shfl_xor(c, off);
    if ((t & 63) == 0) cnt[t >> 6] = c;
    __syncthreads();
    if (t == 0) {
        int s = 0;
        #pragma unroll
        for (int q = 0; q < 16; q++) s += cnt[q];
        *fflag = (s > 700) ? 1 : 0;   // 1 = bf16, 0 = fp32
    }
}

// convert the 8 small float tensors into one fp32 scratch block
// layout (floats): W1 @0 (8192) | as1 @8192 (64) | ad1 @8256 (64) | b1 @8320 (64)
//                  W2 @8384 (2048) | as2 @10432 (32) | ad2 @10464 (32) | b2 @10496 (32)
__global__ void k_conv_small(const void* p2, const void* p3, const void* p4, const void* p5,
                             const void* p6, const void* p7, const void* p8, const void* p9,
                             const int* __restrict__ fflag, float* __restrict__ ws) {
    int i = blockIdx.x * 256 + threadIdx.x;
    if (i >= 10528) return;
    const void* p; int off;
    if (i < 8192)       { p = p2; off = i; }
    else if (i < 8256)  { p = p3; off = i - 8192; }
    else if (i < 8320)  { p = p4; off = i - 8256; }
    else if (i < 8384)  { p = p5; off = i - 8320; }
    else if (i < 10432) { p = p6; off = i - 8384; }
    else if (i < 10464) { p = p7; off = i - 10432; }
    else if (i < 10496) { p = p8; off = i - 10464; }
    else                { p = p9; off = i - 10496; }
    ws[i] = (*fflag) ? bf2f(((const unsigned short*)p)[off]) : ((const float*)p)[off];
}

// ---------- CSR build ----------
__global__ void k_convert(const void* __restrict__ raw, const int* __restrict__ iflag,
                          int* __restrict__ src, int* __restrict__ dst) {
    int e = blockIdx.x * 256 + threadIdx.x;
    if (e >= ET) return;
    if (e >= NE) { int v = e - NE; src[e] = v; dst[e] = v; return; }  // self-loops
    if (*iflag) {
        const long long* p = (const long long*)raw;
        src[e] = (int)p[e];
        dst[e] = (int)p[NE + e];
    } else {
        const int* p = (const int*)raw;
        src[e] = p[e];
        dst[e] = p[NE + e];
    }
}

__global__ void k_hist(const int* __restrict__ dst, int* __restrict__ deg) {
    int e = blockIdx.x * 256 + threadIdx.x;
    if (e < ET) atomicAdd(&deg[dst[e]], 1);
}

__global__ __launch_bounds__(1024) void k_scan(const int* __restrict__ deg,
                                               int* __restrict__ rs, int* __restrict__ cur) {
    __shared__ int wsum[16];
    int t = threadIdx.x;
    int lane = t & 63, wid = t >> 6;
    int carry = 0;
    for (int base = 0; base < NN; base += 1024) {
        int idx = base + t;
        int v = (idx < NN) ? deg[idx] : 0;
        int orig = v;
        #pragma unroll
        for (int d = 1; d < 64; d <<= 1) {
            int u = __shfl_up(v, d);
            if (lane >= d) v += u;
        }
        if (lane == 63) wsum[wid] = v;
        __syncthreads();
        if (wid == 0) {
            int s = (lane < 16) ? wsum[lane] : 0;
            #pragma unroll
            for (int d = 1; d < 16; d <<= 1) {
                int u = __shfl_up(s, d);
                if (lane >= d) s += u;
            }
            if (lane < 16) wsum[lane] = s;   // inclusive wave totals
        }
        __syncthreads();
        int wave_off = (wid == 0) ? 0 : wsum[wid - 1];
        int total = wsum[15];
        int excl = carry + wave_off + (v - orig);
        if (idx < NN) { rs[idx] = excl; cur[idx] = excl; }
        carry += total;
        __syncthreads();
    }
    if (t == 0) rs[NN] = carry;
}

__global__ void k_scatter(const int* __restrict__ src, const int* __restrict__ dst,
                          int* __restrict__ cur, int* __restrict__ csr) {
    int e = blockIdx.x * 256 + threadIdx.x;
    if (e < ET) {
        int pos = atomicAdd(&cur[dst[e]], 1);
        csr[pos] = src[e];
    }
}

// ---------- GEMM1: h1[N,64] = x[N,128] @ W1[128,64] ----------
__global__ __launch_bounds__(256) void k_gemm1(const void* __restrict__ xraw,
                                               const int* __restrict__ fflag,
                                               const float* __restrict__ Wf,
                                               float* __restrict__ h1) {
    __shared__ float Wt[64 * 132];   // Wt[c*132+k]
    __shared__ float xt[32 * 132];   // xt[r*132+k]
    int tid = threadIdx.x;
    int rb = blockIdx.x * 32;
    for (int i = tid; i < 128 * 64; i += 256) {
        int k = i >> 6, c = i & 63;
        Wt[c * 132 + k] = Wf[i];
    }
    if (*fflag) {   // bf16 input
        const unsigned short* xb = (const unsigned short*)xraw;
        for (int i = tid; i < 32 * 16; i += 256) {   // 32 rows * 16 uint4 (8 bf16)
            int r = i >> 4, k8 = i & 15;
            float f[8];
            if (rb + r < NN) {
                uint4 v = ((const uint4*)xb)[(size_t)(rb + r) * 16 + k8];
                f[0] = bf2f((unsigned short)(v.x & 0xffff)); f[1] = bf2f((unsigned short)(v.x >> 16));
                f[2] = bf2f((unsigned short)(v.y & 0xffff)); f[3] = bf2f((unsigned short)(v.y >> 16));
                f[4] = bf2f((unsigned short)(v.z & 0xffff)); f[5] = bf2f((unsigned short)(v.z >> 16));
                f[6] = bf2f((unsigned short)(v.w & 0xffff)); f[7] = bf2f((unsigned short)(v.w >> 16));
            } else {
                #pragma unroll
                for (int q = 0; q < 8; q++) f[q] = 0.f;
            }
            int o = r * 132 + k8 * 8;
            *(float4*)&xt[o]     = make_float4(f[0], f[1], f[2], f[3]);
            *(float4*)&xt[o + 4] = make_float4(f[4], f[5], f[6], f[7]);
        }
    } else {        // fp32 input
        const float* xf = (const float*)xraw;
        for (int i = tid; i < 32 * 32; i += 256) {   // 32 rows * 32 float4
            int r = i >> 5, kq = i & 31;
            float4 v = make_float4(0.f, 0.f, 0.f, 0.f);
            if (rb + r < NN) v = ((const float4*)xf)[(size_t)(rb + r) * 32 + kq];
            *(float4*)&xt[r * 132 + kq * 4] = v;
        }
    }
    __syncthreads();
    int c = tid & 63;
    int rg = tid >> 6;   // 0..3, uniform per wave
    float acc[8];
    #pragma unroll
    for (int j = 0; j < 8; j++) acc[j] = 0.f;
    for (int k = 0; k < 128; k += 4) {
        float4 w = *(const float4*)&Wt[c * 132 + k];
        #pragma unroll
        for (int j = 0; j < 8; j++) {
            float4 xv = *(const float4*)&xt[(rg * 8 + j) * 132 + k];
            acc[j] = fmaf(xv.x, w.x, fmaf(xv.y, w.y, fmaf(xv.z, w.z, fmaf(xv.w, w.w, acc[j]))));
        }
    }
    #pragma unroll
    for (int j = 0; j < 8; j++) {
        int r = rb + rg * 8 + j;
        if (r < NN) h1[(size_t)r * 64 + c] = acc[j];
    }
}

// ---------- GEMM2: h2[N,32] = out1[N,64] @ W2[64,32] ----------
__global__ __launch_bounds__(256) void k_gemm2(const float* __restrict__ in,
                                               const float* __restrict__ Wf,
                                               float* __restrict__ h2) {
    __shared__ float Wt[32 * 68];
    __shared__ float xt[64 * 68];
    int tid = threadIdx.x;
    int rb = blockIdx.x * 64;
    for (int i = tid; i < 64 * 32; i += 256) {
        int k = i >> 5, c = i & 31;
        Wt[c * 68 + k] = Wf[i];
    }
    for (int i = tid; i < 64 * 16; i += 256) {
        int r = i >> 4, kq = i & 15;
        float4 v = make_float4(0.f, 0.f, 0.f, 0.f);
        if (rb + r < NN) v = ((const float4*)in)[(size_t)(rb + r) * 16 + kq];
        *(float4*)&xt[r * 68 + kq * 4] = v;
    }
    __syncthreads();
    int c = tid & 31, rg = tid >> 5;  // rg 0..7
    float acc[8];
    #pragma unroll
    for (int j = 0; j < 8; j++) acc[j] = 0.f;
    for (int k = 0; k < 64; k += 4) {
        float4 w = *(const float4*)&Wt[c * 68 + k];
        #pragma unroll
        for (int j = 0; j < 8; j++) {
            float4 xv = *(const float4*)&xt[(rg * 8 + j) * 68 + k];
            acc[j] = fmaf(xv.x, w.x, fmaf(xv.y, w.y, fmaf(xv.z, w.z, fmaf(xv.w, w.w, acc[j]))));
        }
    }
    #pragma unroll
    for (int j = 0; j < 8; j++) {
        int r = rb + rg * 8 + j;
        if (r < NN) h2[(size_t)r * 32 + c] = acc[j];
    }
}

// ---------- attention logits per node ----------
__global__ void k_al1(const float* __restrict__ h1, const float* __restrict__ asrc,
                      const float* __restrict__ adst,
                      float* __restrict__ als, float* __restrict__ ald) {
    int t = blockIdx.x * 256 + threadIdx.x;
    if (t >= NN * 4) return;
    int n = t >> 2, h = t & 3;
    const float4* hp = (const float4*)(h1 + (size_t)n * 64 + h * 16);
    float s = 0.f, d = 0.f;
    #pragma unroll
    for (int q = 0; q < 4; q++) {
        float4 hv = hp[q];
        float4 av = *(const float4*)(asrc + h * 16 + q * 4);
        float4 dv = *(const float4*)(adst + h * 16 + q * 4);
        s += hv.x * av.x + hv.y * av.y + hv.z * av.z + hv.w * av.w;
        d += hv.x * dv.x + hv.y * dv.y + hv.z * dv.z + hv.w * dv.w;
    }
    als[t] = s; ald[t] = d;
}

__global__ void k_al2(const float* __restrict__ h2, const float* __restrict__ asrc,
                      const float* __restrict__ adst,
                      float* __restrict__ als, float* __restrict__ ald) {
    int t = blockIdx.x * 256 + threadIdx.x;
    if (t >= NN * 4) return;
    int n = t >> 2, h = t & 3;
    const float4* hp = (const float4*)(h2 + (size_t)n * 32 + h * 8);
    float s = 0.f, d = 0.f;
    #pragma unroll
    for (int q = 0; q < 2; q++) {
        float4 hv = hp[q];
        float4 av = *(const float4*)(asrc + h * 8 + q * 4);
        float4 dv = *(const float4*)(adst + h * 8 + q * 4);
        s += hv.x * av.x + hv.y * av.y + hv.z * av.z + hv.w * av.w;
        d += hv.x * dv.x + hv.y * dv.y + hv.z * dv.z + hv.w * dv.w;
    }
    als[t] = s; ald[t] = d;
}

// ---------- layer-1 aggregation: one wave per dst node, lane = channel (64) ----------
__global__ __launch_bounds__(256) void k_agg1(const int* __restrict__ rs, const int* __restrict__ csr,
                                              const float* __restrict__ als, const float* __restrict__ aldv,
                                              const float* __restrict__ h1, const float* __restrict__ b1,
                                              float* __restrict__ out1) {
    int n = (blockIdx.x * 256 + threadIdx.x) >> 6;
    int lane = threadIdx.x & 63;
    if (n >= NN) return;
    int base = rs[n];
    int deg = rs[n + 1] - base;
    float4 ald = *(const float4*)(aldv + 4 * n);
    float m0 = -1e30f, m1 = -1e30f, m2 = -1e30f, m3 = -1e30f;
    for (int i = lane; i < deg; i += 64) {
        int s = csr[base + i];
        float4 a = *(const float4*)(als + 4 * s);
        m0 = fmaxf(m0, lrelu(a.x + ald.x));
        m1 = fmaxf(m1, lrelu(a.y + ald.y));
        m2 = fmaxf(m2, lrelu(a.z + ald.z));
        m3 = fmaxf(m3, lrelu(a.w + ald.w));
    }
    #pragma unroll
    for (int off = 32; off; off >>= 1) {
        m0 = fmaxf(m0, __shfl_xor(m0, off));
        m1 = fmaxf(m1, __shfl_xor(m1, off));
        m2 = fmaxf(m2, __shfl_xor(m2, off));
        m3 = fmaxf(m3, __shfl_xor(m3, off));
    }
    float s0 = 0.f, s1 = 0.f, s2 = 0.f, s3 = 0.f;
    for (int i = lane; i < deg; i += 64) {
        int s = csr[base + i];
        float4 a = *(const float4*)(als + 4 * s);
        s0 += __expf(lrelu(a.x + ald.x) - m0);
        s1 += __expf(lrelu(a.y + ald.y) - m1);
        s2 += __expf(lrelu(a.z + ald.z) - m2);
        s3 += __expf(lrelu(a.w + ald.w) - m3);
    }
    #pragma unroll
    for (int off = 32; off; off >>= 1) {
        s0 += __shfl_xor(s0, off);
        s1 += __shfl_xor(s1, off);
        s2 += __shfl_xor(s2, off);
        s3 += __shfl_xor(s3, off);
    }
    int h = lane >> 4;
    float mh = (h == 0) ? m0 : (h == 1) ? m1 : (h == 2) ? m2 : m3;
    float sh = (h == 0) ? s0 : (h == 1) ? s1 : (h == 2) ? s2 : s3;
    float ah = (h == 0) ? ald.x : (h == 1) ? ald.y : (h == 2) ? ald.z : ald.w;
    float rh = 1.f / (sh + 1e-16f);
    float acc = 0.f;
    for (int e = 0; e < deg; ++e) {
        int s = csr[base + e];
        float av = als[4 * s + h];
        float alpha = __expf(lrelu(av + ah) - mh) * rh;
        acc = fmaf(alpha, h1[(size_t)s * 64 + lane], acc);
    }
    float o = acc + b1[lane];
    out1[(size_t)n * 64 + lane] = fmaxf(o, 0.f);   // fused ReLU (layer-2 input)
}

// ---------- layer-2 aggregation + bias + log_softmax, half-wave per node ----------
__global__ __launch_bounds__(256) void k_agg2(const int* __restrict__ rs, const int* __restrict__ csr,
                                              const float* __restrict__ als, const float* __restrict__ aldv,
                                              const float* __restrict__ h2, const float* __restrict__ b2,
                                              float* __restrict__ out) {
    int n = (blockIdx.x * 256 + threadIdx.x) >> 5;
    int L = threadIdx.x & 31;
    if (n >= NN) return;
    int base = rs[n];
    int deg = rs[n + 1] - base;
    float4 ald = *(const float4*)(aldv + 4 * n);
    float m0 = -1e30f, m1 = -1e30f, m2 = -1e30f, m3 = -1e30f;
    for (int i = L; i < deg; i += 32) {
        int s = csr[base + i];
        float4 a = *(const float4*)(als + 4 * s);
        m0 = fmaxf(m0, lrelu(a.x + ald.x));
        m1 = fmaxf(m1, lrelu(a.y + ald.y));
        m2 = fmaxf(m2, lrelu(a.z + ald.z));
        m3 = fmaxf(m3, lrelu(a.w + ald.w));
    }
    #pragma unroll
    for (int off = 16; off; off >>= 1) {
        m0 = fmaxf(m0, __shfl_xor(m0, off, 32));
        m1 = fmaxf(m1, __shfl_xor(m1, off, 32));
        m2 = fmaxf(m2, __shfl_xor(m2, off, 32));
        m3 = fmaxf(m3, __shfl_xor(m3, off, 32));
    }
    float s0 = 0.f, s1 = 0.f, s2 = 0.f, s3 = 0.f;
    for (int i = L; i < deg; i += 32) {
        int s = csr[base + i];
        float4 a = *(const float4*)(als + 4 * s);
        s0 += __expf(lrelu(a.x + ald.x) - m0);
        s1 += __expf(lrelu(a.y + ald.y) - m1);
        s2 += __expf(lrelu(a.z + ald.z) - m2);
        s3 += __expf(lrelu(a.w + ald.w) - m3);
    }
    #pragma unroll
    for (int off = 16; off; off >>= 1) {
        s0 += __shfl_xor(s0, off, 32);
        s1 += __shfl_xor(s1, off, 32);
        s2 += __shfl_xor(s2, off, 32);
        s3 += __shfl_xor(s3, off, 32);
    }
    int h = L >> 3;
    float mh = (h == 0) ? m0 : (h == 1) ? m1 : (h == 2) ? m2 : m3;
    float sh = (h == 0) ? s0 : (h == 1) ? s1 : (h == 2) ? s2 : s3;
    float ah = (h == 0) ? ald.x : (h == 1) ? ald.y : (h == 2) ? ald.z : ald.w;
    float rh = 1.f / (sh + 1e-16f);
    float acc = 0.f;
    for (int e = 0; e < deg; ++e) {
        int s = csr[base + e];
        float av = als[4 * s + h];
        float alpha = __expf(lrelu(av + ah) - mh) * rh;
        acc = fmaf(alpha, h2[(size_t)s * 32 + L], acc);
    }
    float row = acc + b2[L];
    float mx = row;
    #pragma unroll
    for (int off = 16; off; off >>= 1) mx = fmaxf(mx, __shfl_xor(mx, off, 32));
    float p = __expf(row - mx);
    float sm = p;
    #pragma unroll
    for (int off = 16; off; off >>= 1) sm += __shfl_xor(sm, off, 32);
    out[(size_t)n * 32 + L] = row - mx - logf(sm);
}

extern "C" void kernel_launch(void* const* d_in, const int* in_sizes, int n_in,
                              void* d_out, int out_size, void* d_ws, size_t ws_size,
                              hipStream_t stream) {
    const void* x   = d_in[0];
    const void* ei  = d_in[1];
    float* out = (float*)d_out;

    char* p = (char*)d_ws;
    auto take = [&](size_t b) -> char* {
        char* r = p; p += (b + 255) & ~(size_t)255; return r;
    };
    int*   iflag = (int*)take(sizeof(int));
    int*   fflag = (int*)take(sizeof(int));
    int*   deg   = (int*)take(sizeof(int) * NN);
    int*   rs    = (int*)take(sizeof(int) * (NN + 1));
    int*   cur   = (int*)take(sizeof(int) * NN);
    int*   s32   = (int*)take(sizeof(int) * ET);
    int*   d32   = (int*)take(sizeof(int) * ET);
    int*   csr   = (int*)take(sizeof(int) * ET);
    float* wsm   = (float*)take(sizeof(float) * 10528);
    float* h1    = (float*)take(sizeof(float) * (size_t)NN * 64);
    float* als1  = (float*)take(sizeof(float) * NN * 4);
    float* ald1  = (float*)take(sizeof(float) * NN * 4);
    float* out1  = (float*)take(sizeof(float) * (size_t)NN * 64);
    float* h2    = (float*)take(sizeof(float) * (size_t)NN * 32);
    float* als2  = (float*)take(sizeof(float) * NN * 4);
    float* ald2  = (float*)take(sizeof(float) * NN * 4);

    float* Wf1  = wsm;
    float* as1f = wsm + 8192;
    float* ad1f = wsm + 8256;
    float* b1f  = wsm + 8320;
    float* Wf2  = wsm + 8384;
    float* as2f = wsm + 10432;
    float* ad2f = wsm + 10464;
    float* b2f  = wsm + 10496;

    k_init<<<(NN + 255) / 256, 256, 0, stream>>>(iflag, deg);
    k_fdetect<<<1, 1024, 0, stream>>>((const unsigned int*)x, fflag);
    k_detect<<<(NE + 255) / 256, 256, 0, stream>>>((const unsigned long long*)ei, iflag);
    k_conv_small<<<(10528 + 255) / 256, 256, 0, stream>>>(d_in[2], d_in[3], d_in[4], d_in[5],
                                                          d_in[6], d_in[7], d_in[8], d_in[9],
                                                          fflag, wsm);
    k_convert<<<(ET + 255) / 256, 256, 0, stream>>>(ei, iflag, s32, d32);
    k_hist<<<(ET + 255) / 256, 256, 0, stream>>>(d32, deg);
    k_scan<<<1, 1024, 0, stream>>>(deg, rs, cur);
    k_scatter<<<(ET + 255) / 256, 256, 0, stream>>>(s32, d32, cur, csr);

    k_gemm1<<<(NN + 31) / 32, 256, 0, stream>>>(x, fflag, Wf1, h1);
    k_al1<<<(NN * 4 + 255) / 256, 256, 0, stream>>>(h1, as1f, ad1f, als1, ald1);
    k_agg1<<<(NN * 64) / 256, 256, 0, stream>>>(rs, csr, als1, ald1, h1, b1f, out1);

    k_gemm2<<<(NN + 63) / 64, 256, 0, stream>>>(out1, Wf2, h2);
    k_al2<<<(NN * 4 + 255) / 256, 256, 0, stream>>>(h2, as2f, ad2f, als2, ald2);
    k_agg2<<<(NN * 32) / 256, 256, 0, stream>>>(rs, csr, als2, ald2, h2, b2f, out);
}

// Round 4
// 392.439 us; speedup vs baseline: 1.1349x; 1.1349x over previous
//
#include <hip/hip_runtime.h>
#include <hip/hip_bf16.h>
#include <math.h>

#define NN 50000
#define NE 800000
#define ET (NE + NN)
#define DCAP 128   // fast-path degree cap; fallback handles larger

__device__ __forceinline__ float bf2f(unsigned short u) {
    return __uint_as_float(((unsigned)u) << 16);
}
__device__ __forceinline__ float lrelu(float e) {
    return e >= 0.f ? e : 0.2f * e;
}

// ---------- prep: zero deg, detect int width, detect float dtype ----------
__global__ __launch_bounds__(1024) void k_prep(const unsigned long long* __restrict__ ei,
                                               const unsigned int* __restrict__ x,
                                               int* __restrict__ iflag, int* __restrict__ fflag,
                                               int* __restrict__ deg) {
    int b = blockIdx.x, t = threadIdx.x;
    if (b < 49) {
        int i = b * 1024 + t;
        if (i < NN) deg[i] = 0;
    } else if (b == 49) {
        // int64 values are < NN; int32 pairs read as u64 are >= 2^32 w.p. ~1-2e-5/slot
        __shared__ int any;
        if (t == 0) any = 0;
        __syncthreads();
        if (ei[t] >= (unsigned long long)NN) atomicOr(&any, 1);
        __syncthreads();
        if (t == 0) *iflag = any ? 0 : 1;   // 1 = int64
    } else {
        // fp32 N(0,1): bits14..7 uniform; bf16-pair: exponent concentrated in [96,140]
        __shared__ int cnt[16];
        unsigned w = x[t];
        unsigned e = (w >> 7) & 0xFFu;
        int c = (e >= 96 && e <= 140) ? 1 : 0;
        #pragma unroll
        for (int off = 32; off; off >>= 1) c += __shfl_xor(c, off);
        if ((t & 63) == 0) cnt[t >> 6] = c;
        __syncthreads();
        if (t == 0) {
            int s = 0;
            #pragma unroll
            for (int q = 0; q < 16; q++) s += cnt[q];
            *fflag = (s > 700) ? 1 : 0;   // 1 = bf16, 0 = fp32
        }
    }
}

// ---------- convert edges + histogram + convert small weight tensors ----------
// wsm layout (floats): W1@0(8192) as1@8192(64) ad1@8256(64) b1@8320(64)
//                      W2@8384(2048) as2@10432(32) ad2@10464(32) b2@10496(32)
__global__ void k_convert_hist(const void* __restrict__ raw,
                               const void* p2, const void* p3, const void* p4, const void* p5,
                               const void* p6, const void* p7, const void* p8, const void* p9,
                               const int* __restrict__ iflag, const int* __restrict__ fflag,
                               int* __restrict__ s32, int* __restrict__ d32,
                               int* __restrict__ deg, float* __restrict__ wsm) {
    int e = blockIdx.x * 256 + threadIdx.x;
    if (e < 10528) {
        const void* p; int off;
        if (e < 8192)       { p = p2; off = e; }
        else if (e < 8256)  { p = p3; off = e - 8192; }
        else if (e < 8320)  { p = p4; off = e - 8256; }
        else if (e < 8384)  { p = p5; off = e - 8320; }
        else if (e < 10432) { p = p6; off = e - 8384; }
        else if (e < 10464) { p = p7; off = e - 10432; }
        else if (e < 10496) { p = p8; off = e - 10464; }
        else                { p = p9; off = e - 10496; }
        wsm[e] = (*fflag) ? bf2f(((const unsigned short*)p)[off]) : ((const float*)p)[off];
    }
    if (e >= ET) return;
    int s, d;
    if (e >= NE) { s = d = e - NE; }               // self-loops
    else if (*iflag) {
        s = (int)((const long long*)raw)[e];
        d = (int)((const long long*)raw)[NE + e];
    } else {
        s = ((const int*)raw)[e];
        d = ((const int*)raw)[NE + e];
    }
    s32[e] = s; d32[e] = d;
    atomicAdd(&deg[d], 1);
}

__global__ __launch_bounds__(1024) void k_scan(const int* __restrict__ deg,
                                               int* __restrict__ rs, int* __restrict__ cur) {
    __shared__ int wsum[16];
    int t = threadIdx.x;
    int lane = t & 63, wid = t >> 6;
    int carry = 0;
    for (int base = 0; base < NN; base += 1024) {
        int idx = base + t;
        int v = (idx < NN) ? deg[idx] : 0;
        int orig = v;
        #pragma unroll
        for (int d = 1; d < 64; d <<= 1) {
            int u = __shfl_up(v, d);
            if (lane >= d) v += u;
        }
        if (lane == 63) wsum[wid] = v;
        __syncthreads();
        if (wid == 0) {
            int s = (lane < 16) ? wsum[lane] : 0;
            #pragma unroll
            for (int d = 1; d < 16; d <<= 1) {
                int u = __shfl_up(s, d);
                if (lane >= d) s += u;
            }
            if (lane < 16) wsum[lane] = s;
        }
        __syncthreads();
        int wave_off = (wid == 0) ? 0 : wsum[wid - 1];
        int total = wsum[15];
        int excl = carry + wave_off + (v - orig);
        if (idx < NN) { rs[idx] = excl; cur[idx] = excl; }
        carry += total;
        __syncthreads();
    }
    if (t == 0) rs[NN] = carry;
}

__global__ void k_scatter(const int* __restrict__ src, const int* __restrict__ dst,
                          int* __restrict__ cur, int* __restrict__ csr) {
    int e = blockIdx.x * 256 + threadIdx.x;
    if (e < ET) {
        int pos = atomicAdd(&cur[dst[e]], 1);
        csr[pos] = src[e];
    }
}

// ---------- GEMM1 + fused al1: h1[N,64] = x[N,128]@W1, als/ald via shuffles ----------
__global__ __launch_bounds__(256) void k_gemm1(const void* __restrict__ xraw,
                                               const int* __restrict__ fflag,
                                               const float* __restrict__ Wf,
                                               const float* __restrict__ asf_p,
                                               const float* __restrict__ adf_p,
                                               float* __restrict__ h1,
                                               float* __restrict__ als, float* __restrict__ ald) {
    __shared__ float Wt[64 * 132];   // Wt[c*132+k]
    __shared__ float xt[32 * 132];   // xt[r*132+k]
    int tid = threadIdx.x;
    int rb = blockIdx.x * 32;
    for (int i = tid; i < 128 * 64; i += 256) {
        int k = i >> 6, c = i & 63;
        Wt[c * 132 + k] = Wf[i];
    }
    if (*fflag) {   // bf16 input
        const unsigned short* xb = (const unsigned short*)xraw;
        for (int i = tid; i < 32 * 16; i += 256) {
            int r = i >> 4, k8 = i & 15;
            float f[8];
            if (rb + r < NN) {
                uint4 v = ((const uint4*)xb)[(size_t)(rb + r) * 16 + k8];
                f[0] = bf2f((unsigned short)(v.x & 0xffff)); f[1] = bf2f((unsigned short)(v.x >> 16));
                f[2] = bf2f((unsigned short)(v.y & 0xffff)); f[3] = bf2f((unsigned short)(v.y >> 16));
                f[4] = bf2f((unsigned short)(v.z & 0xffff)); f[5] = bf2f((unsigned short)(v.z >> 16));
                f[6] = bf2f((unsigned short)(v.w & 0xffff)); f[7] = bf2f((unsigned short)(v.w >> 16));
            } else {
                #pragma unroll
                for (int q = 0; q < 8; q++) f[q] = 0.f;
            }
            int o = r * 132 + k8 * 8;
            *(float4*)&xt[o]     = make_float4(f[0], f[1], f[2], f[3]);
            *(float4*)&xt[o + 4] = make_float4(f[4], f[5], f[6], f[7]);
        }
    } else {        // fp32 input
        const float* xf = (const float*)xraw;
        for (int i = tid; i < 32 * 32; i += 256) {
            int r = i >> 5, kq = i & 31;
            float4 v = make_float4(0.f, 0.f, 0.f, 0.f);
            if (rb + r < NN) v = ((const float4*)xf)[(size_t)(rb + r) * 32 + kq];
            *(float4*)&xt[r * 132 + kq * 4] = v;
        }
    }
    __syncthreads();
    int c = tid & 63;
    int rg = tid >> 6;
    float acc[8];
    #pragma unroll
    for (int j = 0; j < 8; j++) acc[j] = 0.f;
    for (int k = 0; k < 128; k += 4) {
        float4 w = *(const float4*)&Wt[c * 132 + k];
        #pragma unroll
        for (int j = 0; j < 8; j++) {
            float4 xv = *(const float4*)&xt[(rg * 8 + j) * 132 + k];
            acc[j] = fmaf(xv.x, w.x, fmaf(xv.y, w.y, fmaf(xv.z, w.z, fmaf(xv.w, w.w, acc[j]))));
        }
    }
    float asf = asf_p[c], adf = adf_p[c];
    #pragma unroll
    for (int j = 0; j < 8; j++) {
        int r = rb + rg * 8 + j;
        bool ok = r < NN;
        if (ok) h1[(size_t)r * 64 + c] = acc[j];
        // fused attention-logit reduction within 16-lane head groups
        float v = acc[j] * asf, w = acc[j] * adf;
        #pragma unroll
        for (int off = 1; off < 16; off <<= 1) {
            v += __shfl_xor(v, off);
            w += __shfl_xor(w, off);
        }
        if (ok && (c & 15) == 0) {
            als[r * 4 + (c >> 4)] = v;
            ald[r * 4 + (c >> 4)] = w;
        }
    }
}

// ---------- GEMM2 + fused al2: h2[N,32] = out1[N,64]@W2 ----------
__global__ __launch_bounds__(256) void k_gemm2(const float* __restrict__ in,
                                               const float* __restrict__ Wf,
                                               const float* __restrict__ asf_p,
                                               const float* __restrict__ adf_p,
                                               float* __restrict__ h2,
                                               float* __restrict__ als, float* __restrict__ ald) {
    __shared__ float Wt[32 * 68];
    __shared__ float xt[64 * 68];
    int tid = threadIdx.x;
    int rb = blockIdx.x * 64;
    for (int i = tid; i < 64 * 32; i += 256) {
        int k = i >> 5, c = i & 31;
        Wt[c * 68 + k] = Wf[i];
    }
    for (int i = tid; i < 64 * 16; i += 256) {
        int r = i >> 4, kq = i & 15;
        float4 v = make_float4(0.f, 0.f, 0.f, 0.f);
        if (rb + r < NN) v = ((const float4*)in)[(size_t)(rb + r) * 16 + kq];
        *(float4*)&xt[r * 68 + kq * 4] = v;
    }
    __syncthreads();
    int c = tid & 31, rg = tid >> 5;
    float acc[8];
    #pragma unroll
    for (int j = 0; j < 8; j++) acc[j] = 0.f;
    for (int k = 0; k < 64; k += 4) {
        float4 w = *(const float4*)&Wt[c * 68 + k];
        #pragma unroll
        for (int j = 0; j < 8; j++) {
            float4 xv = *(const float4*)&xt[(rg * 8 + j) * 68 + k];
            acc[j] = fmaf(xv.x, w.x, fmaf(xv.y, w.y, fmaf(xv.z, w.z, fmaf(xv.w, w.w, acc[j]))));
        }
    }
    float asf = asf_p[c], adf = adf_p[c];
    #pragma unroll
    for (int j = 0; j < 8; j++) {
        int r = rb + rg * 8 + j;
        bool ok = r < NN;
        if (ok) h2[(size_t)r * 32 + c] = acc[j];
        float v = acc[j] * asf, w = acc[j] * adf;
        #pragma unroll
        for (int off = 1; off < 8; off <<= 1) {
            v += __shfl_xor(v, off);
            w += __shfl_xor(w, off);
        }
        if (ok && (c & 7) == 0) {
            als[r * 4 + (c >> 3)] = v;
            ald[r * 4 + (c >> 3)] = w;
        }
    }
}

// ---------- layer-1 aggregation: wave/node, LDS-staged softmax ----------
__global__ __launch_bounds__(256) void k_agg1(const int* __restrict__ rs, const int* __restrict__ csr,
                                              const float* __restrict__ als, const float* __restrict__ aldv,
                                              const float* __restrict__ h1, const float* __restrict__ b1,
                                              float* __restrict__ out1) {
    __shared__ float pv[4][DCAP * 4];
    int w = threadIdx.x >> 6, lane = threadIdx.x & 63;
    int n = blockIdx.x * 4 + w;
    if (n >= NN) return;
    int base = rs[n];
    int deg = rs[n + 1] - base;
    float4 ald = *(const float4*)(aldv + 4 * n);
    int h = lane >> 4;
    float acc = 0.f, rh;

    if (deg <= DCAP) {
        int sA = 0, sB = 0;
        float4 el0, el1;
        bool v0 = lane < deg, v1 = lane + 64 < deg;
        float m0 = -1e30f, m1 = -1e30f, m2 = -1e30f, m3 = -1e30f;
        if (v0) {
            sA = csr[base + lane];
            float4 a = *(const float4*)(als + 4 * sA);
            el0.x = lrelu(a.x + ald.x); el0.y = lrelu(a.y + ald.y);
            el0.z = lrelu(a.z + ald.z); el0.w = lrelu(a.w + ald.w);
            m0 = el0.x; m1 = el0.y; m2 = el0.z; m3 = el0.w;
        }
        if (v1) {
            sB = csr[base + lane + 64];
            float4 a = *(const float4*)(als + 4 * sB);
            el1.x = lrelu(a.x + ald.x); el1.y = lrelu(a.y + ald.y);
            el1.z = lrelu(a.z + ald.z); el1.w = lrelu(a.w + ald.w);
            m0 = fmaxf(m0, el1.x); m1 = fmaxf(m1, el1.y);
            m2 = fmaxf(m2, el1.z); m3 = fmaxf(m3, el1.w);
        }
        #pragma unroll
        for (int off = 32; off; off >>= 1) {
            m0 = fmaxf(m0, __shfl_xor(m0, off));
            m1 = fmaxf(m1, __shfl_xor(m1, off));
            m2 = fmaxf(m2, __shfl_xor(m2, off));
            m3 = fmaxf(m3, __shfl_xor(m3, off));
        }
        float s0 = 0.f, s1 = 0.f, s2 = 0.f, s3 = 0.f;
        if (v0) {
            float4 p;
            p.x = __expf(el0.x - m0); p.y = __expf(el0.y - m1);
            p.z = __expf(el0.z - m2); p.w = __expf(el0.w - m3);
            s0 = p.x; s1 = p.y; s2 = p.z; s3 = p.w;
            *(float4*)&pv[w][lane * 4] = p;
        }
        if (v1) {
            float4 p;
            p.x = __expf(el1.x - m0); p.y = __expf(el1.y - m1);
            p.z = __expf(el1.z - m2); p.w = __expf(el1.w - m3);
            s0 += p.x; s1 += p.y; s2 += p.z; s3 += p.w;
            *(float4*)&pv[w][(lane + 64) * 4] = p;
        }
        #pragma unroll
        for (int off = 32; off; off >>= 1) {
            s0 += __shfl_xor(s0, off);
            s1 += __shfl_xor(s1, off);
            s2 += __shfl_xor(s2, off);
            s3 += __shfl_xor(s3, off);
        }
        float sh = (h == 0) ? s0 : (h == 1) ? s1 : (h == 2) ? s2 : s3;
        rh = 1.f / (sh + 1e-16f);
        // serial aggregate: idx via shuffle (registers), p via LDS broadcast
        for (int e = 0; e < deg; ++e) {
            int s = (e < 64) ? __shfl(sA, e) : __shfl(sB, e - 64);
            float ph = pv[w][e * 4 + h];
            acc = fmaf(ph, h1[(size_t)s * 64 + lane], acc);
        }
    } else {
        // fallback: 3-pass global (rare)
        float m0 = -1e30f, m1 = -1e30f, m2 = -1e30f, m3 = -1e30f;
        for (int i = lane; i < deg; i += 64) {
            int s = csr[base + i];
            float4 a = *(const float4*)(als + 4 * s);
            m0 = fmaxf(m0, lrelu(a.x + ald.x));
            m1 = fmaxf(m1, lrelu(a.y + ald.y));
            m2 = fmaxf(m2, lrelu(a.z + ald.z));
            m3 = fmaxf(m3, lrelu(a.w + ald.w));
        }
        #pragma unroll
        for (int off = 32; off; off >>= 1) {
            m0 = fmaxf(m0, __shfl_xor(m0, off));
            m1 = fmaxf(m1, __shfl_xor(m1, off));
            m2 = fmaxf(m2, __shfl_xor(m2, off));
            m3 = fmaxf(m3, __shfl_xor(m3, off));
        }
        float s0 = 0.f, s1 = 0.f, s2 = 0.f, s3 = 0.f;
        for (int i = lane; i < deg; i += 64) {
            int s = csr[base + i];
            float4 a = *(const float4*)(als + 4 * s);
            s0 += __expf(lrelu(a.x + ald.x) - m0);
            s1 += __expf(lrelu(a.y + ald.y) - m1);
            s2 += __expf(lrelu(a.z + ald.z) - m2);
            s3 += __expf(lrelu(a.w + ald.w) - m3);
        }
        #pragma unroll
        for (int off = 32; off; off >>= 1) {
            s0 += __shfl_xor(s0, off);
            s1 += __shfl_xor(s1, off);
            s2 += __shfl_xor(s2, off);
            s3 += __shfl_xor(s3, off);
        }
        float mh = (h == 0) ? m0 : (h == 1) ? m1 : (h == 2) ? m2 : m3;
        float sh = (h == 0) ? s0 : (h == 1) ? s1 : (h == 2) ? s2 : s3;
        float ah = (h == 0) ? ald.x : (h == 1) ? ald.y : (h == 2) ? ald.z : ald.w;
        rh = 1.f / (sh + 1e-16f);
        for (int e = 0; e < deg; ++e) {
            int s = csr[base + e];
            float av = als[4 * s + h];
            float ph = __expf(lrelu(av + ah) - mh);
            acc = fmaf(ph, h1[(size_t)s * 64 + lane], acc);
        }
    }
    out1[(size_t)n * 64 + lane] = fmaxf(acc * rh + b1[lane], 0.f);   // bias + ReLU
}

// ---------- layer-2 aggregation + bias + log_softmax: half-wave/node ----------
__global__ __launch_bounds__(256) void k_agg2(const int* __restrict__ rs, const int* __restrict__ csr,
                                              const float* __restrict__ als, const float* __restrict__ aldv,
                                              const float* __restrict__ h2, const float* __restrict__ b2,
                                              float* __restrict__ out) {
    __shared__ float pv[8][DCAP * 4];
    int w = threadIdx.x >> 5, L = threadIdx.x & 31;
    int n = blockIdx.x * 8 + w;
    if (n >= NN) return;
    int base = rs[n];
    int deg = rs[n + 1] - base;
    float4 ald = *(const float4*)(aldv + 4 * n);
    int h = L >> 3;
    float acc = 0.f, rh;

    if (deg <= DCAP) {
        int sr[4] = {0, 0, 0, 0};
        float4 el[4];
        bool vv[4];
        float m0 = -1e30f, m1 = -1e30f, m2 = -1e30f, m3 = -1e30f;
        #pragma unroll
        for (int q = 0; q < 4; q++) {
            int i = L + q * 32;
            vv[q] = i < deg;
            if (vv[q]) {
                sr[q] = csr[base + i];
                float4 a = *(const float4*)(als + 4 * sr[q]);
                el[q].x = lrelu(a.x + ald.x); el[q].y = lrelu(a.y + ald.y);
                el[q].z = lrelu(a.z + ald.z); el[q].w = lrelu(a.w + ald.w);
                m0 = fmaxf(m0, el[q].x); m1 = fmaxf(m1, el[q].y);
                m2 = fmaxf(m2, el[q].z); m3 = fmaxf(m3, el[q].w);
            }
        }
        #pragma unroll
        for (int off = 16; off; off >>= 1) {
            m0 = fmaxf(m0, __shfl_xor(m0, off, 32));
            m1 = fmaxf(m1, __shfl_xor(m1, off, 32));
            m2 = fmaxf(m2, __shfl_xor(m2, off, 32));
            m3 = fmaxf(m3, __shfl_xor(m3, off, 32));
        }
        float s0 = 0.f, s1 = 0.f, s2 = 0.f, s3 = 0.f;
        #pragma unroll
        for (int q = 0; q < 4; q++) {
            if (vv[q]) {
                float4 p;
                p.x = __expf(el[q].x - m0); p.y = __expf(el[q].y - m1);
                p.z = __expf(el[q].z - m2); p.w = __expf(el[q].w - m3);
                s0 += p.x; s1 += p.y; s2 += p.z; s3 += p.w;
                *(float4*)&pv[w][(L + q * 32) * 4] = p;
            }
        }
        #pragma unroll
        for (int off = 16; off; off >>= 1) {
            s0 += __shfl_xor(s0, off, 32);
            s1 += __shfl_xor(s1, off, 32);
            s2 += __shfl_xor(s2, off, 32);
            s3 += __shfl_xor(s3, off, 32);
        }
        float sh = (h == 0) ? s0 : (h == 1) ? s1 : (h == 2) ? s2 : s3;
        rh = 1.f / (sh + 1e-16f);
        for (int e = 0; e < deg; ++e) {
            int s = __shfl(sr[e >> 5], e & 31, 32);
            float ph = pv[w][e * 4 + h];
            acc = fmaf(ph, h2[(size_t)s * 32 + L], acc);
        }
    } else {
        float m0 = -1e30f, m1 = -1e30f, m2 = -1e30f, m3 = -1e30f;
        for (int i = L; i < deg; i += 32) {
            int s = csr[base + i];
            float4 a = *(const float4*)(als + 4 * s);
            m0 = fmaxf(m0, lrelu(a.x + ald.x));
            m1 = fmaxf(m1, lrelu(a.y + ald.y));
            m2 = fmaxf(m2, lrelu(a.z + ald.z));
            m3 = fmaxf(m3, lrelu(a.w + ald.w));
        }
        #pragma unroll
        for (int off = 16; off; off >>= 1) {
            m0 = fmaxf(m0, __shfl_xor(m0, off, 32));
            m1 = fmaxf(m1, __shfl_xor(m1, off, 32));
            m2 = fmaxf(m2, __shfl_xor(m2, off, 32));
            m3 = fmaxf(m3, __shfl_xor(m3, off, 32));
        }
        float s0 = 0.f, s1 = 0.f, s2 = 0.f, s3 = 0.f;
        for (int i = L; i < deg; i += 32) {
            int s = csr[base + i];
            float4 a = *(const float4*)(als + 4 * s);
            s0 += __expf(lrelu(a.x + ald.x) - m0);
            s1 += __expf(lrelu(a.y + ald.y) - m1);
            s2 += __expf(lrelu(a.z + ald.z) - m2);
            s3 += __expf(lrelu(a.w + ald.w) - m3);
        }
        #pragma unroll
        for (int off = 16; off; off >>= 1) {
            s0 += __shfl_xor(s0, off, 32);
            s1 += __shfl_xor(s1, off, 32);
            s2 += __shfl_xor(s2, off, 32);
            s3 += __shfl_xor(s3, off, 32);
        }
        float mh = (h == 0) ? m0 : (h == 1) ? m1 : (h == 2) ? m2 : m3;
        float sh = (h == 0) ? s0 : (h == 1) ? s1 : (h == 2) ? s2 : s3;
        float ah = (h == 0) ? ald.x : (h == 1) ? ald.y : (h == 2) ? ald.z : ald.w;
        rh = 1.f / (sh + 1e-16f);
        for (int e = 0; e < deg; ++e) {
            int s = csr[base + e];
            float av = als[4 * s + h];
            float ph = __expf(lrelu(av + ah) - mh);
            acc = fmaf(ph, h2[(size_t)s * 32 + L], acc);
        }
    }
    float row = acc * rh + b2[L];
    float mx = row;
    #pragma unroll
    for (int off = 16; off; off >>= 1) mx = fmaxf(mx, __shfl_xor(mx, off, 32));
    float p = __expf(row - mx);
    float sm = p;
    #pragma unroll
    for (int off = 16; off; off >>= 1) sm += __shfl_xor(sm, off, 32);
    out[(size_t)n * 32 + L] = row - mx - logf(sm);
}

extern "C" void kernel_launch(void* const* d_in, const int* in_sizes, int n_in,
                              void* d_out, int out_size, void* d_ws, size_t ws_size,
                              hipStream_t stream) {
    const void* x  = d_in[0];
    const void* ei = d_in[1];
    float* out = (float*)d_out;

    char* p = (char*)d_ws;
    auto take = [&](size_t b) -> char* {
        char* r = p; p += (b + 255) & ~(size_t)255; return r;
    };
    int*   iflag = (int*)take(sizeof(int));
    int*   fflag = (int*)take(sizeof(int));
    int*   deg   = (int*)take(sizeof(int) * NN);
    int*   rs    = (int*)take(sizeof(int) * (NN + 1));
    int*   cur   = (int*)take(sizeof(int) * NN);
    int*   s32   = (int*)take(sizeof(int) * ET);
    int*   d32   = (int*)take(sizeof(int) * ET);
    int*   csr   = (int*)take(sizeof(int) * ET);
    float* wsm   = (float*)take(sizeof(float) * 10528);
    float* h1    = (float*)take(sizeof(float) * (size_t)NN * 64);
    float* als1  = (float*)take(sizeof(float) * NN * 4);
    float* ald1  = (float*)take(sizeof(float) * NN * 4);
    float* out1  = (float*)take(sizeof(float) * (size_t)NN * 64);
    float* h2    = (float*)take(sizeof(float) * (size_t)NN * 32);
    float* als2  = (float*)take(sizeof(float) * NN * 4);
    float* ald2  = (float*)take(sizeof(float) * NN * 4);

    float* Wf1  = wsm;
    float* as1f = wsm + 8192;
    float* ad1f = wsm + 8256;
    float* b1f  = wsm + 8320;
    float* Wf2  = wsm + 8384;
    float* as2f = wsm + 10432;
    float* ad2f = wsm + 10464;
    float* b2f  = wsm + 10496;

    k_prep<<<51, 1024, 0, stream>>>((const unsigned long long*)ei, (const unsigned int*)x,
                                    iflag, fflag, deg);
    k_convert_hist<<<(ET + 255) / 256, 256, 0, stream>>>(ei, d_in[2], d_in[3], d_in[4], d_in[5],
                                                         d_in[6], d_in[7], d_in[8], d_in[9],
                                                         iflag, fflag, s32, d32, deg, wsm);
    k_scan<<<1, 1024, 0, stream>>>(deg, rs, cur);
    k_scatter<<<(ET + 255) / 256, 256, 0, stream>>>(s32, d32, cur, csr);

    k_gemm1<<<(NN + 31) / 32, 256, 0, stream>>>(x, fflag, Wf1, as1f, ad1f, h1, als1, ald1);
    k_agg1<<<(NN + 3) / 4, 256, 0, stream>>>(rs, csr, als1, ald1, h1, b1f, out1);

    k_gemm2<<<(NN + 63) / 64, 256, 0, stream>>>(out1, Wf2, as2f, ad2f, h2, als2, ald2);
    k_agg2<<<(NN + 7) / 8, 256, 0, stream>>>(rs, csr, als2, ald2, h2, b2f, out);
}

// Round 5
// 313.450 us; speedup vs baseline: 1.4209x; 1.2520x over previous
//
#include <hip/hip_runtime.h>
#include <hip/hip_bf16.h>
#include <math.h>

#define NN 50000
#define NE 800000
#define ET (NE + NN)
#define DCAP 128   // fast-path degree cap; fallback handles larger
#define SG 196     // scan grid: ceil(NN/256)

__device__ __forceinline__ float bf2f(unsigned short u) {
    return __uint_as_float(((unsigned)u) << 16);
}
__device__ __forceinline__ float lrelu(float e) {
    return e >= 0.f ? e : 0.2f * e;
}

// ---------- prep: zero deg, detect int width, detect float dtype ----------
__global__ __launch_bounds__(1024) void k_prep(const unsigned long long* __restrict__ ei,
                                               const unsigned int* __restrict__ x,
                                               int* __restrict__ iflag, int* __restrict__ fflag,
                                               int* __restrict__ deg) {
    int b = blockIdx.x, t = threadIdx.x;
    if (b < 49) {
        int i = b * 1024 + t;
        if (i < NN) deg[i] = 0;
    } else if (b == 49) {
        __shared__ int any;
        if (t == 0) any = 0;
        __syncthreads();
        if (ei[t] >= (unsigned long long)NN) atomicOr(&any, 1);
        __syncthreads();
        if (t == 0) *iflag = any ? 0 : 1;   // 1 = int64
    } else {
        // fp32 N(0,1): bits14..7 uniform; bf16-pair: exponent concentrated in [96,140]
        __shared__ int cnt[16];
        unsigned w = x[t];
        unsigned e = (w >> 7) & 0xFFu;
        int c = (e >= 96 && e <= 140) ? 1 : 0;
        #pragma unroll
        for (int off = 32; off; off >>= 1) c += __shfl_xor(c, off);
        if ((t & 63) == 0) cnt[t >> 6] = c;
        __syncthreads();
        if (t == 0) {
            int s = 0;
            #pragma unroll
            for (int q = 0; q < 16; q++) s += cnt[q];
            *fflag = (s > 700) ? 1 : 0;   // 1 = bf16, 0 = fp32
        }
    }
}

// ---------- convert edges + histogram + convert small weight tensors ----------
__global__ void k_convert_hist(const void* __restrict__ raw,
                               const void* p2, const void* p3, const void* p4, const void* p5,
                               const void* p6, const void* p7, const void* p8, const void* p9,
                               const int* __restrict__ iflag, const int* __restrict__ fflag,
                               int* __restrict__ s32, int* __restrict__ d32,
                               int* __restrict__ deg, float* __restrict__ wsm) {
    int e = blockIdx.x * 256 + threadIdx.x;
    if (e < 10528) {
        const void* p; int off;
        if (e < 8192)       { p = p2; off = e; }
        else if (e < 8256)  { p = p3; off = e - 8192; }
        else if (e < 8320)  { p = p4; off = e - 8256; }
        else if (e < 8384)  { p = p5; off = e - 8320; }
        else if (e < 10432) { p = p6; off = e - 8384; }
        else if (e < 10464) { p = p7; off = e - 10432; }
        else if (e < 10496) { p = p8; off = e - 10464; }
        else                { p = p9; off = e - 10496; }
        wsm[e] = (*fflag) ? bf2f(((const unsigned short*)p)[off]) : ((const float*)p)[off];
    }
    if (e >= ET) return;
    int s, d;
    if (e >= NE) { s = d = e - NE; }               // self-loops
    else if (*iflag) {
        s = (int)((const long long*)raw)[e];
        d = (int)((const long long*)raw)[NE + e];
    } else {
        s = ((const int*)raw)[e];
        d = ((const int*)raw)[NE + e];
    }
    s32[e] = s; d32[e] = d;
    atomicAdd(&deg[d], 1);
}

// ---------- parallel scan: up / mid / down ----------
__device__ __forceinline__ int block_excl_scan(int v, int* lds, int t) {
    int lane = t & 63, wid = t >> 6;
    int inc = v;
    #pragma unroll
    for (int d = 1; d < 64; d <<= 1) {
        int u = __shfl_up(inc, d);
        if (lane >= d) inc += u;
    }
    if (lane == 63) lds[wid] = inc;
    __syncthreads();
    if (t == 0) {
        int a = lds[0], b = lds[1], c = lds[2];
        lds[4] = 0; lds[5] = a; lds[6] = a + b; lds[7] = a + b + c;
    }
    __syncthreads();
    return lds[4 + wid] + inc - v;
}

__global__ __launch_bounds__(256) void k_scan_up(const int* __restrict__ deg, int* __restrict__ bsum) {
    __shared__ int lds[8];
    int t = threadIdx.x, i = blockIdx.x * 256 + t;
    int v = (i < NN) ? deg[i] : 0;
    #pragma unroll
    for (int off = 32; off; off >>= 1) v += __shfl_xor(v, off);
    if ((t & 63) == 0) lds[t >> 6] = v;
    __syncthreads();
    if (t == 0) bsum[blockIdx.x] = lds[0] + lds[1] + lds[2] + lds[3];
}

__global__ __launch_bounds__(256) void k_scan_mid(const int* __restrict__ bsum, int* __restrict__ boff) {
    __shared__ int lds[8];
    int t = threadIdx.x;
    int v = (t < SG) ? bsum[t] : 0;
    int e = block_excl_scan(v, lds, t);
    if (t < SG) boff[t] = e;
}

__global__ __launch_bounds__(256) void k_scan_down(const int* __restrict__ deg, const int* __restrict__ boff,
                                                   int* __restrict__ rs, int* __restrict__ cur) {
    __shared__ int lds[8];
    int t = threadIdx.x, i = blockIdx.x * 256 + t;
    int v = (i < NN) ? deg[i] : 0;
    int e = block_excl_scan(v, lds, t) + boff[blockIdx.x];
    if (i < NN) {
        rs[i] = e; cur[i] = e;
        if (i == NN - 1) rs[NN] = e + v;
    }
}

__global__ void k_scatter(const int* __restrict__ src, const int* __restrict__ dst,
                          int* __restrict__ cur, int* __restrict__ csr) {
    int e = blockIdx.x * 256 + threadIdx.x;
    if (e < ET) {
        int pos = atomicAdd(&cur[dst[e]], 1);
        csr[pos] = src[e];
    }
}

// ---------- GEMM1 + fused al1: h1[N,64] = x[N,128]@W1 ----------
__global__ __launch_bounds__(256) void k_gemm1(const void* __restrict__ xraw,
                                               const int* __restrict__ fflag,
                                               const float* __restrict__ Wf,
                                               const float* __restrict__ asf_p,
                                               const float* __restrict__ adf_p,
                                               float* __restrict__ h1,
                                               float* __restrict__ als, float* __restrict__ ald) {
    __shared__ float Wt[64 * 129];   // stride 129: bank (c+k)%32 -> conflict-free b32 reads
    __shared__ float xt[32 * 132];   // stride 132: b128-aligned, reads are wave-broadcast
    int tid = threadIdx.x;
    int rb = blockIdx.x * 32;
    for (int i = tid; i < 128 * 64; i += 256) {
        int k = i >> 6, c = i & 63;
        Wt[c * 129 + k] = Wf[i];
    }
    if (*fflag) {   // bf16 input
        const unsigned short* xb = (const unsigned short*)xraw;
        for (int i = tid; i < 32 * 16; i += 256) {
            int r = i >> 4, k8 = i & 15;
            float f[8];
            if (rb + r < NN) {
                uint4 v = ((const uint4*)xb)[(size_t)(rb + r) * 16 + k8];
                f[0] = bf2f((unsigned short)(v.x & 0xffff)); f[1] = bf2f((unsigned short)(v.x >> 16));
                f[2] = bf2f((unsigned short)(v.y & 0xffff)); f[3] = bf2f((unsigned short)(v.y >> 16));
                f[4] = bf2f((unsigned short)(v.z & 0xffff)); f[5] = bf2f((unsigned short)(v.z >> 16));
                f[6] = bf2f((unsigned short)(v.w & 0xffff)); f[7] = bf2f((unsigned short)(v.w >> 16));
            } else {
                #pragma unroll
                for (int q = 0; q < 8; q++) f[q] = 0.f;
            }
            int o = r * 132 + k8 * 8;
            *(float4*)&xt[o]     = make_float4(f[0], f[1], f[2], f[3]);
            *(float4*)&xt[o + 4] = make_float4(f[4], f[5], f[6], f[7]);
        }
    } else {        // fp32 input
        const float* xf = (const float*)xraw;
        for (int i = tid; i < 32 * 32; i += 256) {
            int r = i >> 5, kq = i & 31;
            float4 v = make_float4(0.f, 0.f, 0.f, 0.f);
            if (rb + r < NN) v = ((const float4*)xf)[(size_t)(rb + r) * 32 + kq];
            *(float4*)&xt[r * 132 + kq * 4] = v;
        }
    }
    __syncthreads();
    int c = tid & 63;
    int rg = tid >> 6;
    float acc[8];
    #pragma unroll
    for (int j = 0; j < 8; j++) acc[j] = 0.f;
    for (int k = 0; k < 128; k += 4) {
        float4 w;
        w.x = Wt[c * 129 + k];     w.y = Wt[c * 129 + k + 1];
        w.z = Wt[c * 129 + k + 2]; w.w = Wt[c * 129 + k + 3];
        #pragma unroll
        for (int j = 0; j < 8; j++) {
            float4 xv = *(const float4*)&xt[(rg * 8 + j) * 132 + k];
            acc[j] = fmaf(xv.x, w.x, fmaf(xv.y, w.y, fmaf(xv.z, w.z, fmaf(xv.w, w.w, acc[j]))));
        }
    }
    float asf = asf_p[c], adf = adf_p[c];
    #pragma unroll
    for (int j = 0; j < 8; j++) {
        int r = rb + rg * 8 + j;
        bool ok = r < NN;
        if (ok) h1[(size_t)r * 64 + c] = acc[j];
        float v = acc[j] * asf, w = acc[j] * adf;
        #pragma unroll
        for (int off = 1; off < 16; off <<= 1) {
            v += __shfl_xor(v, off);
            w += __shfl_xor(w, off);
        }
        if (ok && (c & 15) == 0) {
            als[r * 4 + (c >> 4)] = v;
            ald[r * 4 + (c >> 4)] = w;
        }
    }
}

// ---------- GEMM2 + fused al2: h2[N,32] = out1[N,64]@W2 ----------
__global__ __launch_bounds__(256) void k_gemm2(const float* __restrict__ in,
                                               const float* __restrict__ Wf,
                                               const float* __restrict__ asf_p,
                                               const float* __restrict__ adf_p,
                                               float* __restrict__ h2,
                                               float* __restrict__ als, float* __restrict__ ald) {
    __shared__ float Wt[32 * 65];    // stride 65: conflict-free b32 reads
    __shared__ float xt[64 * 68];
    int tid = threadIdx.x;
    int rb = blockIdx.x * 64;
    for (int i = tid; i < 64 * 32; i += 256) {
        int k = i >> 5, c = i & 31;
        Wt[c * 65 + k] = Wf[i];
    }
    for (int i = tid; i < 64 * 16; i += 256) {
        int r = i >> 4, kq = i & 15;
        float4 v = make_float4(0.f, 0.f, 0.f, 0.f);
        if (rb + r < NN) v = ((const float4*)in)[(size_t)(rb + r) * 16 + kq];
        *(float4*)&xt[r * 68 + kq * 4] = v;
    }
    __syncthreads();
    int c = tid & 31, rg = tid >> 5;
    float acc[8];
    #pragma unroll
    for (int j = 0; j < 8; j++) acc[j] = 0.f;
    for (int k = 0; k < 64; k += 4) {
        float4 w;
        w.x = Wt[c * 65 + k];     w.y = Wt[c * 65 + k + 1];
        w.z = Wt[c * 65 + k + 2]; w.w = Wt[c * 65 + k + 3];
        #pragma unroll
        for (int j = 0; j < 8; j++) {
            float4 xv = *(const float4*)&xt[(rg * 8 + j) * 68 + k];
            acc[j] = fmaf(xv.x, w.x, fmaf(xv.y, w.y, fmaf(xv.z, w.z, fmaf(xv.w, w.w, acc[j]))));
        }
    }
    float asf = asf_p[c], adf = adf_p[c];
    #pragma unroll
    for (int j = 0; j < 8; j++) {
        int r = rb + rg * 8 + j;
        bool ok = r < NN;
        if (ok) h2[(size_t)r * 32 + c] = acc[j];
        float v = acc[j] * asf, w = acc[j] * adf;
        #pragma unroll
        for (int off = 1; off < 8; off <<= 1) {
            v += __shfl_xor(v, off);
            w += __shfl_xor(w, off);
        }
        if (ok && (c & 7) == 0) {
            als[r * 4 + (c >> 3)] = v;
            ald[r * 4 + (c >> 3)] = w;
        }
    }
}

// ---------- layer-1 aggregation: wave/node, LDS-staged softmax, MLP-4 ----------
__global__ __launch_bounds__(256) void k_agg1(const int* __restrict__ rs, const int* __restrict__ csr,
                                              const float* __restrict__ als, const float* __restrict__ aldv,
                                              const float* __restrict__ h1, const float* __restrict__ b1,
                                              float* __restrict__ out1) {
    __shared__ float pv[4][DCAP * 4];
    int w = threadIdx.x >> 6, lane = threadIdx.x & 63;
    int n = blockIdx.x * 4 + w;
    if (n >= NN) return;
    int base = rs[n];
    int deg = rs[n + 1] - base;
    float4 ald = *(const float4*)(aldv + 4 * n);
    int h = lane >> 4;
    float acc = 0.f, rh;

    if (deg <= DCAP) {
        int sA = 0, sB = 0;
        float4 el0, el1;
        bool v0 = lane < deg, v1 = lane + 64 < deg;
        float m0 = -1e30f, m1 = -1e30f, m2 = -1e30f, m3 = -1e30f;
        if (v0) {
            sA = csr[base + lane];
            float4 a = *(const float4*)(als + 4 * sA);
            el0.x = lrelu(a.x + ald.x); el0.y = lrelu(a.y + ald.y);
            el0.z = lrelu(a.z + ald.z); el0.w = lrelu(a.w + ald.w);
            m0 = el0.x; m1 = el0.y; m2 = el0.z; m3 = el0.w;
        }
        if (v1) {
            sB = csr[base + lane + 64];
            float4 a = *(const float4*)(als + 4 * sB);
            el1.x = lrelu(a.x + ald.x); el1.y = lrelu(a.y + ald.y);
            el1.z = lrelu(a.z + ald.z); el1.w = lrelu(a.w + ald.w);
            m0 = fmaxf(m0, el1.x); m1 = fmaxf(m1, el1.y);
            m2 = fmaxf(m2, el1.z); m3 = fmaxf(m3, el1.w);
        }
        #pragma unroll
        for (int off = 32; off; off >>= 1) {
            m0 = fmaxf(m0, __shfl_xor(m0, off));
            m1 = fmaxf(m1, __shfl_xor(m1, off));
            m2 = fmaxf(m2, __shfl_xor(m2, off));
            m3 = fmaxf(m3, __shfl_xor(m3, off));
        }
        float s0 = 0.f, s1 = 0.f, s2 = 0.f, s3 = 0.f;
        if (v0) {
            float4 p;
            p.x = __expf(el0.x - m0); p.y = __expf(el0.y - m1);
            p.z = __expf(el0.z - m2); p.w = __expf(el0.w - m3);
            s0 = p.x; s1 = p.y; s2 = p.z; s3 = p.w;
            *(float4*)&pv[w][lane * 4] = p;
        }
        if (v1) {
            float4 p;
            p.x = __expf(el1.x - m0); p.y = __expf(el1.y - m1);
            p.z = __expf(el1.z - m2); p.w = __expf(el1.w - m3);
            s0 += p.x; s1 += p.y; s2 += p.z; s3 += p.w;
            *(float4*)&pv[w][(lane + 64) * 4] = p;
        }
        #pragma unroll
        for (int off = 32; off; off >>= 1) {
            s0 += __shfl_xor(s0, off);
            s1 += __shfl_xor(s1, off);
            s2 += __shfl_xor(s2, off);
            s3 += __shfl_xor(s3, off);
        }
        float sh = (h == 0) ? s0 : (h == 1) ? s1 : (h == 2) ? s2 : s3;
        rh = 1.f / (sh + 1e-16f);
        // serial aggregate, unrolled x4 with independent accumulators (MLP)
        float a0 = 0.f, a1 = 0.f, a2 = 0.f, a3 = 0.f;
        int e = 0;
        for (; e + 4 <= deg; e += 4) {
            int t0 = (e     < 64) ? __shfl(sA, e)     : __shfl(sB, e - 64);
            int t1 = (e + 1 < 64) ? __shfl(sA, e + 1) : __shfl(sB, e - 63);
            int t2 = (e + 2 < 64) ? __shfl(sA, e + 2) : __shfl(sB, e - 62);
            int t3 = (e + 3 < 64) ? __shfl(sA, e + 3) : __shfl(sB, e - 61);
            float p0 = pv[w][(e    ) * 4 + h], p1 = pv[w][(e + 1) * 4 + h];
            float p2 = pv[w][(e + 2) * 4 + h], p3 = pv[w][(e + 3) * 4 + h];
            float f0 = h1[(size_t)t0 * 64 + lane];
            float f1 = h1[(size_t)t1 * 64 + lane];
            float f2 = h1[(size_t)t2 * 64 + lane];
            float f3 = h1[(size_t)t3 * 64 + lane];
            a0 = fmaf(p0, f0, a0); a1 = fmaf(p1, f1, a1);
            a2 = fmaf(p2, f2, a2); a3 = fmaf(p3, f3, a3);
        }
        for (; e < deg; ++e) {
            int s = (e < 64) ? __shfl(sA, e) : __shfl(sB, e - 64);
            a0 = fmaf(pv[w][e * 4 + h], h1[(size_t)s * 64 + lane], a0);
        }
        acc = (a0 + a1) + (a2 + a3);
    } else {
        // fallback: 3-pass global (rare)
        float m0 = -1e30f, m1 = -1e30f, m2 = -1e30f, m3 = -1e30f;
        for (int i = lane; i < deg; i += 64) {
            int s = csr[base + i];
            float4 a = *(const float4*)(als + 4 * s);
            m0 = fmaxf(m0, lrelu(a.x + ald.x));
            m1 = fmaxf(m1, lrelu(a.y + ald.y));
            m2 = fmaxf(m2, lrelu(a.z + ald.z));
            m3 = fmaxf(m3, lrelu(a.w + ald.w));
        }
        #pragma unroll
        for (int off = 32; off; off >>= 1) {
            m0 = fmaxf(m0, __shfl_xor(m0, off));
            m1 = fmaxf(m1, __shfl_xor(m1, off));
            m2 = fmaxf(m2, __shfl_xor(m2, off));
            m3 = fmaxf(m3, __shfl_xor(m3, off));
        }
        float s0 = 0.f, s1 = 0.f, s2 = 0.f, s3 = 0.f;
        for (int i = lane; i < deg; i += 64) {
            int s = csr[base + i];
            float4 a = *(const float4*)(als + 4 * s);
            s0 += __expf(lrelu(a.x + ald.x) - m0);
            s1 += __expf(lrelu(a.y + ald.y) - m1);
            s2 += __expf(lrelu(a.z + ald.z) - m2);
            s3 += __expf(lrelu(a.w + ald.w) - m3);
        }
        #pragma unroll
        for (int off = 32; off; off >>= 1) {
            s0 += __shfl_xor(s0, off);
            s1 += __shfl_xor(s1, off);
            s2 += __shfl_xor(s2, off);
            s3 += __shfl_xor(s3, off);
        }
        float mh = (h == 0) ? m0 : (h == 1) ? m1 : (h == 2) ? m2 : m3;
        float sh = (h == 0) ? s0 : (h == 1) ? s1 : (h == 2) ? s2 : s3;
        float ah = (h == 0) ? ald.x : (h == 1) ? ald.y : (h == 2) ? ald.z : ald.w;
        rh = 1.f / (sh + 1e-16f);
        for (int e = 0; e < deg; ++e) {
            int s = csr[base + e];
            float av = als[4 * s + h];
            float ph = __expf(lrelu(av + ah) - mh);
            acc = fmaf(ph, h1[(size_t)s * 64 + lane], acc);
        }
    }
    out1[(size_t)n * 64 + lane] = fmaxf(acc * rh + b1[lane], 0.f);   // bias + ReLU
}

// ---------- layer-2 aggregation + bias + log_softmax: half-wave/node, MLP-4 ----------
__global__ __launch_bounds__(256) void k_agg2(const int* __restrict__ rs, const int* __restrict__ csr,
                                              const float* __restrict__ als, const float* __restrict__ aldv,
                                              const float* __restrict__ h2, const float* __restrict__ b2,
                                              float* __restrict__ out) {
    __shared__ float pv[8][DCAP * 4];
    int w = threadIdx.x >> 5, L = threadIdx.x & 31;
    int n = blockIdx.x * 8 + w;
    if (n >= NN) return;
    int base = rs[n];
    int deg = rs[n + 1] - base;
    float4 ald = *(const float4*)(aldv + 4 * n);
    int h = L >> 3;
    float acc = 0.f, rh;

    if (deg <= DCAP) {
        int sr[4] = {0, 0, 0, 0};
        float4 el[4];
        bool vv[4];
        float m0 = -1e30f, m1 = -1e30f, m2 = -1e30f, m3 = -1e30f;
        #pragma unroll
        for (int q = 0; q < 4; q++) {
            int i = L + q * 32;
            vv[q] = i < deg;
            if (vv[q]) {
                sr[q] = csr[base + i];
                float4 a = *(const float4*)(als + 4 * sr[q]);
                el[q].x = lrelu(a.x + ald.x); el[q].y = lrelu(a.y + ald.y);
                el[q].z = lrelu(a.z + ald.z); el[q].w = lrelu(a.w + ald.w);
                m0 = fmaxf(m0, el[q].x); m1 = fmaxf(m1, el[q].y);
                m2 = fmaxf(m2, el[q].z); m3 = fmaxf(m3, el[q].w);
            }
        }
        #pragma unroll
        for (int off = 16; off; off >>= 1) {
            m0 = fmaxf(m0, __shfl_xor(m0, off, 32));
            m1 = fmaxf(m1, __shfl_xor(m1, off, 32));
            m2 = fmaxf(m2, __shfl_xor(m2, off, 32));
            m3 = fmaxf(m3, __shfl_xor(m3, off, 32));
        }
        float s0 = 0.f, s1 = 0.f, s2 = 0.f, s3 = 0.f;
        #pragma unroll
        for (int q = 0; q < 4; q++) {
            if (vv[q]) {
                float4 p;
                p.x = __expf(el[q].x - m0); p.y = __expf(el[q].y - m1);
                p.z = __expf(el[q].z - m2); p.w = __expf(el[q].w - m3);
                s0 += p.x; s1 += p.y; s2 += p.z; s3 += p.w;
                *(float4*)&pv[w][(L + q * 32) * 4] = p;
            }
        }
        #pragma unroll
        for (int off = 16; off; off >>= 1) {
            s0 += __shfl_xor(s0, off, 32);
            s1 += __shfl_xor(s1, off, 32);
            s2 += __shfl_xor(s2, off, 32);
            s3 += __shfl_xor(s3, off, 32);
        }
        float sh = (h == 0) ? s0 : (h == 1) ? s1 : (h == 2) ? s2 : s3;
        rh = 1.f / (sh + 1e-16f);
        float a0 = 0.f, a1 = 0.f, a2 = 0.f, a3 = 0.f;
        int e = 0;
        for (; e + 4 <= deg; e += 4) {
            int t0 = __shfl(sr[(e    ) >> 5], (e    ) & 31, 32);
            int t1 = __shfl(sr[(e + 1) >> 5], (e + 1) & 31, 32);
            int t2 = __shfl(sr[(e + 2) >> 5], (e + 2) & 31, 32);
            int t3 = __shfl(sr[(e + 3) >> 5], (e + 3) & 31, 32);
            float p0 = pv[w][(e    ) * 4 + h], p1 = pv[w][(e + 1) * 4 + h];
            float p2 = pv[w][(e + 2) * 4 + h], p3 = pv[w][(e + 3) * 4 + h];
            float f0 = h2[(size_t)t0 * 32 + L];
            float f1 = h2[(size_t)t1 * 32 + L];
            float f2 = h2[(size_t)t2 * 32 + L];
            float f3 = h2[(size_t)t3 * 32 + L];
            a0 = fmaf(p0, f0, a0); a1 = fmaf(p1, f1, a1);
            a2 = fmaf(p2, f2, a2); a3 = fmaf(p3, f3, a3);
        }
        for (; e < deg; ++e) {
            int s = __shfl(sr[e >> 5], e & 31, 32);
            a0 = fmaf(pv[w][e * 4 + h], h2[(size_t)s * 32 + L], a0);
        }
        acc = (a0 + a1) + (a2 + a3);
    } else {
        float m0 = -1e30f, m1 = -1e30f, m2 = -1e30f, m3 = -1e30f;
        for (int i = L; i < deg; i += 32) {
            int s = csr[base + i];
            float4 a = *(const float4*)(als + 4 * s);
            m0 = fmaxf(m0, lrelu(a.x + ald.x));
            m1 = fmaxf(m1, lrelu(a.y + ald.y));
            m2 = fmaxf(m2, lrelu(a.z + ald.z));
            m3 = fmaxf(m3, lrelu(a.w + ald.w));
        }
        #pragma unroll
        for (int off = 16; off; off >>= 1) {
            m0 = fmaxf(m0, __shfl_xor(m0, off, 32));
            m1 = fmaxf(m1, __shfl_xor(m1, off, 32));
            m2 = fmaxf(m2, __shfl_xor(m2, off, 32));
            m3 = fmaxf(m3, __shfl_xor(m3, off, 32));
        }
        float s0 = 0.f, s1 = 0.f, s2 = 0.f, s3 = 0.f;
        for (int i = L; i < deg; i += 32) {
            int s = csr[base + i];
            float4 a = *(const float4*)(als + 4 * s);
            s0 += __expf(lrelu(a.x + ald.x) - m0);
            s1 += __expf(lrelu(a.y + ald.y) - m1);
            s2 += __expf(lrelu(a.z + ald.z) - m2);
            s3 += __expf(lrelu(a.w + ald.w) - m3);
        }
        #pragma unroll
        for (int off = 16; off; off >>= 1) {
            s0 += __shfl_xor(s0, off, 32);
            s1 += __shfl_xor(s1, off, 32);
            s2 += __shfl_xor(s2, off, 32);
            s3 += __shfl_xor(s3, off, 32);
        }
        float mh = (h == 0) ? m0 : (h == 1) ? m1 : (h == 2) ? m2 : m3;
        float sh = (h == 0) ? s0 : (h == 1) ? s1 : (h == 2) ? s2 : s3;
        float ah = (h == 0) ? ald.x : (h == 1) ? ald.y : (h == 2) ? ald.z : ald.w;
        rh = 1.f / (sh + 1e-16f);
        for (int e = 0; e < deg; ++e) {
            int s = csr[base + e];
            float av = als[4 * s + h];
            float ph = __expf(lrelu(av + ah) - mh);
            acc = fmaf(ph, h2[(size_t)s * 32 + L], acc);
        }
    }
    float row = acc * rh + b2[L];
    float mx = row;
    #pragma unroll
    for (int off = 16; off; off >>= 1) mx = fmaxf(mx, __shfl_xor(mx, off, 32));
    float p = __expf(row - mx);
    float sm = p;
    #pragma unroll
    for (int off = 16; off; off >>= 1) sm += __shfl_xor(sm, off, 32);
    out[(size_t)n * 32 + L] = row - mx - logf(sm);
}

extern "C" void kernel_launch(void* const* d_in, const int* in_sizes, int n_in,
                              void* d_out, int out_size, void* d_ws, size_t ws_size,
                              hipStream_t stream) {
    const void* x  = d_in[0];
    const void* ei = d_in[1];
    float* out = (float*)d_out;

    char* p = (char*)d_ws;
    auto take = [&](size_t b) -> char* {
        char* r = p; p += (b + 255) & ~(size_t)255; return r;
    };
    int*   iflag = (int*)take(sizeof(int));
    int*   fflag = (int*)take(sizeof(int));
    int*   deg   = (int*)take(sizeof(int) * NN);
    int*   rs    = (int*)take(sizeof(int) * (NN + 1));
    int*   cur   = (int*)take(sizeof(int) * NN);
    int*   bsum  = (int*)take(sizeof(int) * 256);
    int*   boff  = (int*)take(sizeof(int) * 256);
    int*   s32   = (int*)take(sizeof(int) * ET);
    int*   d32   = (int*)take(sizeof(int) * ET);
    int*   csr   = (int*)take(sizeof(int) * ET);
    float* wsm   = (float*)take(sizeof(float) * 10528);
    float* h1    = (float*)take(sizeof(float) * (size_t)NN * 64);
    float* als1  = (float*)take(sizeof(float) * NN * 4);
    float* ald1  = (float*)take(sizeof(float) * NN * 4);
    float* out1  = (float*)take(sizeof(float) * (size_t)NN * 64);
    float* h2    = (float*)take(sizeof(float) * (size_t)NN * 32);
    float* als2  = (float*)take(sizeof(float) * NN * 4);
    float* ald2  = (float*)take(sizeof(float) * NN * 4);

    float* Wf1  = wsm;
    float* as1f = wsm + 8192;
    float* ad1f = wsm + 8256;
    float* b1f  = wsm + 8320;
    float* Wf2  = wsm + 8384;
    float* as2f = wsm + 10432;
    float* ad2f = wsm + 10464;
    float* b2f  = wsm + 10496;

    k_prep<<<51, 1024, 0, stream>>>((const unsigned long long*)ei, (const unsigned int*)x,
                                    iflag, fflag, deg);
    k_convert_hist<<<(ET + 255) / 256, 256, 0, stream>>>(ei, d_in[2], d_in[3], d_in[4], d_in[5],
                                                         d_in[6], d_in[7], d_in[8], d_in[9],
                                                         iflag, fflag, s32, d32, deg, wsm);
    k_scan_up<<<SG, 256, 0, stream>>>(deg, bsum);
    k_scan_mid<<<1, 256, 0, stream>>>(bsum, boff);
    k_scan_down<<<SG, 256, 0, stream>>>(deg, boff, rs, cur);
    k_scatter<<<(ET + 255) / 256, 256, 0, stream>>>(s32, d32, cur, csr);

    k_gemm1<<<(NN + 31) / 32, 256, 0, stream>>>(x, fflag, Wf1, as1f, ad1f, h1, als1, ald1);
    k_agg1<<<(NN + 3) / 4, 256, 0, stream>>>(rs, csr, als1, ald1, h1, b1f, out1);

    k_gemm2<<<(NN + 63) / 64, 256, 0, stream>>>(out1, Wf2, as2f, ad2f, h2, als2, ald2);
    k_agg2<<<(NN + 7) / 8, 256, 0, stream>>>(rs, csr, als2, ald2, h2, b2f, out);
}